// Round 3
// baseline (603.209 us; speedup 1.0000x reference)
//
#include <hip/hip_runtime.h>

#define B_  512
#define D_  256
#define O_  256
#define H2_ 1024

typedef __attribute__((ext_vector_type(4))) float  f32x4;
typedef __attribute__((ext_vector_type(8))) short  short8;
typedef __attribute__((ext_vector_type(4))) short  short4v;
typedef unsigned short ushort_t;

union S8u  { short4v v; unsigned u[2]; };
union S16u { short8  v; unsigned u[4]; };

// fp32 -> bf16 round-to-nearest-even on raw bits (finite inputs only)
__device__ __forceinline__ unsigned f32_bf16(float x) {
  unsigned u = __builtin_bit_cast(unsigned, x);
  return (u + 0x7fffu + ((u >> 16) & 1u)) >> 16;
}
__device__ __forceinline__ unsigned cvt_pk_bf16(float a, float b) {
  return f32_bf16(a) | (f32_bf16(b) << 16);
}

// async global->LDS, 16B per lane, wave-uniform LDS base + lane*16
__device__ __forceinline__ void gload_lds16(const void* g, void* l) {
  __builtin_amdgcn_global_load_lds(
      (const __attribute__((address_space(1))) unsigned*)g,
      (__attribute__((address_space(3))) unsigned*)l, 16, 0, 0);
}

// ---------------------------------------------------------------------------
// Generic small GEMM: C[M,N] = act(A[M,K] @ B[N,K]^T + bias[N]); fp32 in/out,
// bf16 MFMA inside. 64x64 tile per block, 256 threads = 4 waves, each wave a
// 32x32 quadrant (2x2 of 16x16x32 mfma), BK=64. (unchanged — verified passing)
// ---------------------------------------------------------------------------
template <int RELU>
__global__ __launch_bounds__(256)
void gemm_bt64(const float* __restrict__ A, const float* __restrict__ Bm,
               const float* __restrict__ bias, float* __restrict__ C,
               int M, int N, int K) {
  __shared__ __align__(16) short As[64][72];
  __shared__ __align__(16) short Bs[64][72];
  const int t    = threadIdx.x;
  const int m0   = blockIdx.y * 64;
  const int n0   = blockIdx.x * 64;
  const int f4c  = t & 15;
  const int rg   = t >> 4;
  const int lane = t & 63;
  const int w    = t >> 6;
  const int wm   = (w & 1) * 32;
  const int wn   = (w >> 1) * 32;
  const int lr   = lane & 15;
  const int lq   = lane >> 4;

  f32x4 acc[2][2];
  #pragma unroll
  for (int i = 0; i < 2; ++i)
    #pragma unroll
    for (int j = 0; j < 2; ++j) acc[i][j] = f32x4{0.f, 0.f, 0.f, 0.f};

  for (int k0 = 0; k0 < K; k0 += 64) {
    #pragma unroll
    for (int j = 0; j < 4; ++j) {
      int r = rg + 16 * j;
      f32x4 av = *(const f32x4*)(A  + (size_t)(m0 + r) * K + k0 + f4c * 4);
      f32x4 bv = *(const f32x4*)(Bm + (size_t)(n0 + r) * K + k0 + f4c * 4);
      S8u sa; sa.u[0] = cvt_pk_bf16(av.x, av.y); sa.u[1] = cvt_pk_bf16(av.z, av.w);
      S8u sb; sb.u[0] = cvt_pk_bf16(bv.x, bv.y); sb.u[1] = cvt_pk_bf16(bv.z, bv.w);
      *(short4v*)&As[r][f4c * 4] = sa.v;
      *(short4v*)&Bs[r][f4c * 4] = sb.v;
    }
    __syncthreads();
    #pragma unroll
    for (int ks = 0; ks < 2; ++ks) {
      short8 a0 = *(const short8*)&As[wm + lr     ][ks * 32 + lq * 8];
      short8 a1 = *(const short8*)&As[wm + 16 + lr][ks * 32 + lq * 8];
      short8 b0 = *(const short8*)&Bs[wn + lr     ][ks * 32 + lq * 8];
      short8 b1 = *(const short8*)&Bs[wn + 16 + lr][ks * 32 + lq * 8];
      acc[0][0] = __builtin_amdgcn_mfma_f32_16x16x32_bf16(a0, b0, acc[0][0], 0, 0, 0);
      acc[0][1] = __builtin_amdgcn_mfma_f32_16x16x32_bf16(a0, b1, acc[0][1], 0, 0, 0);
      acc[1][0] = __builtin_amdgcn_mfma_f32_16x16x32_bf16(a1, b0, acc[1][0], 0, 0, 0);
      acc[1][1] = __builtin_amdgcn_mfma_f32_16x16x32_bf16(a1, b1, acc[1][1], 0, 0, 0);
    }
    __syncthreads();
  }
  #pragma unroll
  for (int mi = 0; mi < 2; ++mi)
    #pragma unroll
    for (int ni = 0; ni < 2; ++ni)
      #pragma unroll
      for (int r = 0; r < 4; ++r) {
        int row = m0 + wm + mi * 16 + lq * 4 + r;
        int col = n0 + wn + ni * 16 + lr;
        float v = acc[mi][ni][r] + bias[col];
        if (RELU) v = fmaxf(v, 0.f);
        C[(size_t)row * N + col] = v;
      }
}

// ---------------------------------------------------------------------------
// out[b,o] += sum_d input[b,d] * b_d[d*O+o]   (one block per b row, verified)
// ---------------------------------------------------------------------------
__global__ __launch_bounds__(256)
void bias_d_kernel(const float* __restrict__ inp, const float* __restrict__ b_d,
                   float* __restrict__ out) {
  const int b = blockIdx.x;
  const int o = threadIdx.x;
  const float* ir = inp + (size_t)b * D_;
  float s = 0.f;
  for (int d = 0; d < D_; ++d)
    s += ir[d] * b_d[(size_t)d * O_ + o];
  out[(size_t)b * O_ + o] += s;
}

// ---------------------------------------------------------------------------
// Bulk fp32 -> bf16 conversion (x2 only; 1 MB out, ~2 us)
// ---------------------------------------------------------------------------
__global__ __launch_bounds__(256)
void cvt_f32_bf16(const float* __restrict__ in, ushort_t* __restrict__ out, int n8) {
  for (size_t i = (size_t)blockIdx.x * 256 + threadIdx.x; i < (size_t)n8;
       i += (size_t)gridDim.x * 256) {
    const float* p = in + i * 8;
    f32x4 v0 = *(const f32x4*)p;
    f32x4 v1 = *(const f32x4*)(p + 4);
    S16u s;
    s.u[0] = cvt_pk_bf16(v0.x, v0.y);
    s.u[1] = cvt_pk_bf16(v0.z, v0.w);
    s.u[2] = cvt_pk_bf16(v1.x, v1.y);
    s.u[3] = cvt_pk_bf16(v1.z, v1.w);
    *(short8*)(out + i * 8) = s.v;
  }
}

// ---------------------------------------------------------------------------
// Stage B v4: pure bilinear contraction, d as a COLUMN-block coordinate.
//   Block (mt, nb): out-rows [mt*256,+256), N-tile = 16 d x 16 o:
//     d0 = (nb>>4)*16, og = (nb&15)*16.
//   acc[b, n] = sum_h x2b[b,h] * Wd[(d0+(n>>4))*256 + og + (n&15)][h], K=1024.
//   Epilogue: out[b, og+(n&15)] += sum over the 16 d (8 per wn-half folded
//   in-register) of inp[b,d] * acc  -> atomicAdd (4.2M total).
// 512 thr = 8 waves (4 wm x 2 wn), wave tile 64x128, acc[4][8] = 128 VGPR.
// K-loop: 32 iters of BK=32; A via global_load_lds dbuf (issued 1 iter ahead),
// B reg-staged fp32->bf16 (issued 1 iter ahead); raw s_barrier + COUNTED
// vmcnt (never 0 in steady state) so load latency hides under a full iter.
// LDS 64KB total; XOR swizzle for 64B rows: slot = cg ^ ((row>>1)&3), applied
// to DMA source, ds_write slot, and ds_read slot (both-sides, rule 21).
// mt-siblings (lin, lin+256) share the whole B-panel and land on the same XCD
// (256 % 8 == 0) -> W_d served once per XCD L2.
// ---------------------------------------------------------------------------
__global__ __launch_bounds__(512, 2)
void stage_b4(const ushort_t* __restrict__ x2b, const float* __restrict__ inp,
              const float* __restrict__ Wd, float* __restrict__ out) {
  __shared__ __align__(16) ushort_t As[2][256 * 32];   // 2 x 16KB
  __shared__ __align__(16) ushort_t Bs[2][256 * 32];   // 2 x 16KB
  const int t    = threadIdx.x;
  const int lin  = blockIdx.x + 8 * blockIdx.y;   // 0..511
  const int mt   = lin >> 8;                      // 0..1
  const int nb   = lin & 255;
  const int d0   = (nb >> 4) * 16;
  const int og   = (nb & 15) * 16;
  const int bm   = mt * 256;
  const int lane = t & 63;
  const int w    = t >> 6;            // 0..7
  const int wm   = (w >> 1) * 64;     // M quadrant
  const int wn   = (w & 1) * 128;     // N half
  const int lr   = lane & 15;
  const int lq   = lane >> 4;         // 0..3

  // ---- A staging (DMA): wave w, call c stages rows w*32+c*16+(lane>>2),
  // 4 lanes per 64B row; source col-group pre-swizzled (involution).
  const int arow = lane >> 2;                       // 0..15
  const int aswz = (lane & 3) ^ ((lane >> 3) & 3);  // cg ^ ((row>>1)&3)
  const ushort_t* a_src0 = x2b + (size_t)(bm + (w & 3) * 0) * 0;  // unused
  const ushort_t* aptr[2];
  #pragma unroll
  for (int c = 0; c < 2; ++c)
    aptr[c] = x2b + (size_t)(bm + w * 32 + c * 16 + arow) * H2_ + aswz * 8;

  // ---- B staging: thread covers LDS row rr = t>>1, h-half hh = t&1 (16 f32).
  const int rr = t >> 1;
  const int hh = t & 1;
  const int wr = (d0 + (rr >> 4)) * 256 + og + (rr & 15);   // W_d row
  const float* bptr = Wd + (size_t)wr * H2_ + hh * 16;
  const int bsw = (rr >> 1) & 3;                            // write swizzle

  // ---- fragment-read swizzled slot (same for A and B: rows are wm/wn+mi*16+lr)
  const int sl = (lq ^ ((lr >> 1) & 3)) * 8;

  f32x4 acc[4][8];
  #pragma unroll
  for (int mi = 0; mi < 4; ++mi)
    #pragma unroll
    for (int nj = 0; nj < 8; ++nj) acc[mi][nj] = f32x4{0.f, 0.f, 0.f, 0.f};

  f32x4 breg[4];

  auto stageA = [&](int k, int bf) {
    #pragma unroll
    for (int c = 0; c < 2; ++c)
      gload_lds16(aptr[c] + k * 32, &As[bf][(w * 32 + c * 16) * 32]);
  };
  auto loadB = [&](int k) {
    const float* p = bptr + k * 32;
    breg[0] = *(const f32x4*)p;
    breg[1] = *(const f32x4*)(p + 4);
    breg[2] = *(const f32x4*)(p + 8);
    breg[3] = *(const f32x4*)(p + 12);
  };
  auto writeB = [&](int bf) {
    S16u s0, s1;
    s0.u[0] = cvt_pk_bf16(breg[0].x, breg[0].y);
    s0.u[1] = cvt_pk_bf16(breg[0].z, breg[0].w);
    s0.u[2] = cvt_pk_bf16(breg[1].x, breg[1].y);
    s0.u[3] = cvt_pk_bf16(breg[1].z, breg[1].w);
    s1.u[0] = cvt_pk_bf16(breg[2].x, breg[2].y);
    s1.u[1] = cvt_pk_bf16(breg[2].z, breg[2].w);
    s1.u[2] = cvt_pk_bf16(breg[3].x, breg[3].y);
    s1.u[3] = cvt_pk_bf16(breg[3].z, breg[3].w);
    const int lcg0 = hh * 2;
    *(short8*)&Bs[bf][rr * 32 + (lcg0 ^ bsw) * 8]       = s0.v;
    *(short8*)&Bs[bf][rr * 32 + ((lcg0 + 1) ^ bsw) * 8] = s1.v;
  };

  // ---- prologue
  stageA(0, 0);
  __builtin_amdgcn_sched_barrier(0);
  loadB(0);
  __builtin_amdgcn_sched_barrier(0);
  asm volatile("s_waitcnt vmcnt(0)" ::: "memory");
  writeB(0);
  loadB(1);                                   // B(1) in flight
  __builtin_amdgcn_sched_barrier(0);
  asm volatile("s_waitcnt lgkmcnt(0)" ::: "memory");
  __builtin_amdgcn_s_barrier();

  int buf = 0;
  for (int k = 0; k < 32; ++k) {
    // entry: As[buf]=A(k), Bs[buf]=B(k) ready; breg holds B(k+1) in flight(4)
    if (k < 31) {
      stageA(k + 1, buf ^ 1);                 // +2 vmem (per wave)
      __builtin_amdgcn_sched_barrier(0);
      asm volatile("s_waitcnt vmcnt(2)" ::: "memory");   // B(k+1) regs ready
      writeB(buf ^ 1);
    }
    if (k < 30) {
      loadB(k + 2);                           // +4 vmem
      __builtin_amdgcn_sched_barrier(0);
    }

    // MFMA phase on buf: 12 ds_read_b128 + 32 MFMA
    short8 af[4], bf[8];
    #pragma unroll
    for (int mi = 0; mi < 4; ++mi)
      af[mi] = *(const short8*)&As[buf][(wm + mi * 16 + lr) * 32 + sl];
    #pragma unroll
    for (int nj = 0; nj < 8; ++nj)
      bf[nj] = *(const short8*)&Bs[buf][(wn + nj * 16 + lr) * 32 + sl];
    #pragma unroll
    for (int mi = 0; mi < 4; ++mi)
      #pragma unroll
      for (int nj = 0; nj < 8; ++nj)
        acc[mi][nj] = __builtin_amdgcn_mfma_f32_16x16x32_bf16(af[mi], bf[nj],
                                                              acc[mi][nj], 0, 0, 0);

    if (k < 31) {
      if (k < 30) { asm volatile("s_waitcnt vmcnt(4)" ::: "memory"); }
      else        { asm volatile("s_waitcnt vmcnt(0)" ::: "memory"); }
      asm volatile("s_waitcnt lgkmcnt(0)" ::: "memory");
      __builtin_amdgcn_s_barrier();
      buf ^= 1;
    }
  }

  // ---- epilogue: fold 8 d per wn-half in-register, one atomicAdd per (row,o)
  const int dbase = d0 + (w & 1) * 8;
  const int o     = og + lr;
  #pragma unroll
  for (int mi = 0; mi < 4; ++mi)
    #pragma unroll
    for (int r = 0; r < 4; ++r) {
      const int row = bm + wm + mi * 16 + lq * 4 + r;
      f32x4 s0 = *(const f32x4*)(inp + (size_t)row * D_ + dbase);
      f32x4 s1 = *(const f32x4*)(inp + (size_t)row * D_ + dbase + 4);
      float v = s0.x * acc[mi][0][r] + s0.y * acc[mi][1][r] +
                s0.z * acc[mi][2][r] + s0.w * acc[mi][3][r] +
                s1.x * acc[mi][4][r] + s1.y * acc[mi][5][r] +
                s1.z * acc[mi][6][r] + s1.w * acc[mi][7][r];
      atomicAdd(out + (size_t)row * O_ + o, v);
    }
}

extern "C" void kernel_launch(void* const* d_in, const int* in_sizes, int n_in,
                              void* d_out, int out_size, void* d_ws, size_t ws_size,
                              hipStream_t stream) {
  const float* input = (const float*)d_in[0];   // [512,256]
  const float* nanf  = (const float*)d_in[1];   // [512,256]
  const float* W_in  = (const float*)d_in[3];   // [512,256]
  const float* b_in  = (const float*)d_in[4];
  const float* W_h1  = (const float*)d_in[5];   // [1024,512]
  const float* b_h1  = (const float*)d_in[6];
  const float* W_h2  = (const float*)d_in[7];   // [1024,1024]
  const float* b_h2  = (const float*)d_in[8];
  const float* W_d   = (const float*)d_in[9];   // [65536,1024]
  const float* b_d   = (const float*)d_in[10];  // [65536]
  const float* W_b   = (const float*)d_in[11];  // [256,1024]
  const float* b_b   = (const float*)d_in[12];  // [256]
  float* out = (float*)d_out;                   // [512,256]

  float* x0 = (float*)d_ws;                     // [512,512]   1 MB
  float* x1 = x0 + 512 * 512;                   // [512,1024]  2 MB
  float* x2 = x1 + 512 * 1024;                  // [512,1024]  2 MB
  ushort_t* x2b = (ushort_t*)(x2 + 512 * 1024); // [512,1024] bf16, 1 MB

  // Stage A: MLP (~2 GFLOP, serial-dependent)
  gemm_bt64<1><<<dim3(512 / 64, 512 / 64), 256, 0, stream>>>(nanf, W_in, b_in, x0, 512, 512, 256);
  gemm_bt64<1><<<dim3(1024 / 64, 512 / 64), 256, 0, stream>>>(x0, W_h1, b_h1, x1, 512, 1024, 512);
  gemm_bt64<1><<<dim3(1024 / 64, 512 / 64), 256, 0, stream>>>(x1, W_h2, b_h2, x2, 512, 1024, 1024);
  cvt_f32_bf16<<<256, 256, 0, stream>>>(x2, x2b, 512 * 1024 / 8);
  // out = x2 @ W_b^T + b_b  (writes every element of poisoned d_out)
  gemm_bt64<0><<<dim3(256 / 64, 512 / 64), 256, 0, stream>>>(x2, W_b, b_b, out, 512, 256, 1024);
  // out += input @ reshape(b_d, [D,O])
  bias_d_kernel<<<512, 256, 0, stream>>>(input, b_d, out);
  // Stage B: bilinear contraction (atomicAdd into out)
  stage_b4<<<dim3(8, 64), 512, 0, stream>>>(x2b, input, W_d, out);
}

// Round 4
// 584.134 us; speedup vs baseline: 1.0327x; 1.0327x over previous
//
#include <hip/hip_runtime.h>

#define B_  512
#define D_  256
#define O_  256
#define H2_ 1024

typedef __attribute__((ext_vector_type(4))) float  f32x4;
typedef __attribute__((ext_vector_type(8))) short  short8;
typedef __attribute__((ext_vector_type(4))) short  short4v;
typedef unsigned short ushort_t;

union S8u  { short4v v; unsigned u[2]; };
union S16u { short8  v; unsigned u[4]; };

// fp32 -> bf16 round-to-nearest-even on raw bits (finite inputs only)
__device__ __forceinline__ unsigned f32_bf16(float x) {
  unsigned u = __builtin_bit_cast(unsigned, x);
  return (u + 0x7fffu + ((u >> 16) & 1u)) >> 16;
}
__device__ __forceinline__ unsigned cvt_pk_bf16(float a, float b) {
  return f32_bf16(a) | (f32_bf16(b) << 16);
}

// async global->LDS, 16B per lane, wave-uniform LDS base + lane*16
__device__ __forceinline__ void gload_lds16(const void* g, void* l) {
  __builtin_amdgcn_global_load_lds(
      (const __attribute__((address_space(1))) unsigned*)g,
      (__attribute__((address_space(3))) unsigned*)l, 16, 0, 0);
}

// ---------------------------------------------------------------------------
// Generic small GEMM: C[M,N] = act(A[M,K] @ B[N,K]^T + bias[N]); fp32 in/out,
// bf16 MFMA inside. 64x64 tile per block, 256 threads = 4 waves, each wave a
// 32x32 quadrant (2x2 of 16x16x32 mfma), BK=64. (unchanged — verified passing)
// ---------------------------------------------------------------------------
template <int RELU>
__global__ __launch_bounds__(256)
void gemm_bt64(const float* __restrict__ A, const float* __restrict__ Bm,
               const float* __restrict__ bias, float* __restrict__ C,
               int M, int N, int K) {
  __shared__ __align__(16) short As[64][72];
  __shared__ __align__(16) short Bs[64][72];
  const int t    = threadIdx.x;
  const int m0   = blockIdx.y * 64;
  const int n0   = blockIdx.x * 64;
  const int f4c  = t & 15;
  const int rg   = t >> 4;
  const int lane = t & 63;
  const int w    = t >> 6;
  const int wm   = (w & 1) * 32;
  const int wn   = (w >> 1) * 32;
  const int lr   = lane & 15;
  const int lq   = lane >> 4;

  f32x4 acc[2][2];
  #pragma unroll
  for (int i = 0; i < 2; ++i)
    #pragma unroll
    for (int j = 0; j < 2; ++j) acc[i][j] = f32x4{0.f, 0.f, 0.f, 0.f};

  for (int k0 = 0; k0 < K; k0 += 64) {
    #pragma unroll
    for (int j = 0; j < 4; ++j) {
      int r = rg + 16 * j;
      f32x4 av = *(const f32x4*)(A  + (size_t)(m0 + r) * K + k0 + f4c * 4);
      f32x4 bv = *(const f32x4*)(Bm + (size_t)(n0 + r) * K + k0 + f4c * 4);
      S8u sa; sa.u[0] = cvt_pk_bf16(av.x, av.y); sa.u[1] = cvt_pk_bf16(av.z, av.w);
      S8u sb; sb.u[0] = cvt_pk_bf16(bv.x, bv.y); sb.u[1] = cvt_pk_bf16(bv.z, bv.w);
      *(short4v*)&As[r][f4c * 4] = sa.v;
      *(short4v*)&Bs[r][f4c * 4] = sb.v;
    }
    __syncthreads();
    #pragma unroll
    for (int ks = 0; ks < 2; ++ks) {
      short8 a0 = *(const short8*)&As[wm + lr     ][ks * 32 + lq * 8];
      short8 a1 = *(const short8*)&As[wm + 16 + lr][ks * 32 + lq * 8];
      short8 b0 = *(const short8*)&Bs[wn + lr     ][ks * 32 + lq * 8];
      short8 b1 = *(const short8*)&Bs[wn + 16 + lr][ks * 32 + lq * 8];
      acc[0][0] = __builtin_amdgcn_mfma_f32_16x16x32_bf16(a0, b0, acc[0][0], 0, 0, 0);
      acc[0][1] = __builtin_amdgcn_mfma_f32_16x16x32_bf16(a0, b1, acc[0][1], 0, 0, 0);
      acc[1][0] = __builtin_amdgcn_mfma_f32_16x16x32_bf16(a1, b0, acc[1][0], 0, 0, 0);
      acc[1][1] = __builtin_amdgcn_mfma_f32_16x16x32_bf16(a1, b1, acc[1][1], 0, 0, 0);
    }
    __syncthreads();
  }
  #pragma unroll
  for (int mi = 0; mi < 2; ++mi)
    #pragma unroll
    for (int ni = 0; ni < 2; ++ni)
      #pragma unroll
      for (int r = 0; r < 4; ++r) {
        int row = m0 + wm + mi * 16 + lq * 4 + r;
        int col = n0 + wn + ni * 16 + lr;
        float v = acc[mi][ni][r] + bias[col];
        if (RELU) v = fmaxf(v, 0.f);
        C[(size_t)row * N + col] = v;
      }
}

// ---------------------------------------------------------------------------
// Bulk fp32 -> bf16 conversion (x2 only; 1 MB out, ~2 us)
// ---------------------------------------------------------------------------
__global__ __launch_bounds__(256)
void cvt_f32_bf16(const float* __restrict__ in, ushort_t* __restrict__ out, int n8) {
  for (size_t i = (size_t)blockIdx.x * 256 + threadIdx.x; i < (size_t)n8;
       i += (size_t)gridDim.x * 256) {
    const float* p = in + i * 8;
    f32x4 v0 = *(const f32x4*)p;
    f32x4 v1 = *(const f32x4*)(p + 4);
    S16u s;
    s.u[0] = cvt_pk_bf16(v0.x, v0.y);
    s.u[1] = cvt_pk_bf16(v0.z, v0.w);
    s.u[2] = cvt_pk_bf16(v1.x, v1.y);
    s.u[3] = cvt_pk_bf16(v1.z, v1.w);
    *(short8*)(out + i * 8) = s.v;
  }
}

// ---------------------------------------------------------------------------
// Stage B v5: bilinear contraction, d as column-block; SMALL blocks for TLP.
//   Block (mt, nb): out-rows [mt*128,+128), N-tile 128 = 8 d x 16 o:
//     d0=(nb>>4)*8, og=(nb&15)*16.  acc = x2b @ Wd_rows^T over K=1024.
//   Epilogue: out[row, og+lr] += sum_nj inp[row,d]*(acc[.][nj][.] + b_d[d,o])
//   (folds bias_d for free), atomicAdd.
// 256 thr = 4 waves (2M x 2N), wave tile 64x64, acc[4][4] = 64 AGPR.
// BK=32, LDS 32 KB total, launch_bounds(256,3) -> ~3 blocks/CU: independent
// barrier domains cover each other's vmem waits (v4 failed at 1 block/CU).
// K-loop: A via global_load_lds dbuf, B reg-staged fp32->bf16, both issued at
// top of iter, ONE vmcnt(0)+barrier at iter end (drain lands after MFMA).
// XOR swizzle slot^=((row>>1)&3) on DMA source, ds_write, ds_read (rule 21;
// zero conflicts verified in v4 with identical scheme).
// Dispatch swizzle: x=bx (XCD), q=by; mt=q&3, nb=(q>>2)*8+x -> the 4
// mt-siblings sharing a W_d panel are consecutive slots on ONE XCD.
// ---------------------------------------------------------------------------
__global__ __launch_bounds__(256, 3)
void stage_b5(const ushort_t* __restrict__ x2b, const float* __restrict__ inp,
              const float* __restrict__ Wd, const float* __restrict__ bd,
              float* __restrict__ out) {
  __shared__ __align__(16) ushort_t As[2][128 * 32];   // 2 x 8KB
  __shared__ __align__(16) ushort_t Bs[2][128 * 32];   // 2 x 8KB
  const int t    = threadIdx.x;
  const int x    = blockIdx.x;              // XCD id under %8 round-robin
  const int q    = blockIdx.y;
  const int mt   = q & 3;
  const int nb   = (q >> 2) * 8 + x;        // 0..511
  const int d0   = (nb >> 4) * 8;
  const int og   = (nb & 15) * 16;
  const int bm   = mt * 128;
  const int lane = t & 63;
  const int w    = t >> 6;                  // 0..3
  const int wm   = (w >> 1) * 64;
  const int wn   = (w & 1) * 64;
  const int lr   = lane & 15;
  const int lq   = lane >> 4;

  // A staging (DMA): wave w, call c stages rows w*32+c*16+arow (16 rows/call,
  // 4 lanes x 16B per 64B row); source col-group pre-swizzled (involution).
  const int arow = lane >> 2;                       // 0..15
  const int aswz = (lane & 3) ^ ((arow >> 1) & 3);
  const ushort_t* aptr[2];
  #pragma unroll
  for (int c = 0; c < 2; ++c)
    aptr[c] = x2b + (size_t)(bm + w * 32 + c * 16 + arow) * H2_ + aswz * 8;

  // B staging: thread covers LDS row rr=t>>1 (n-index), h-half hh=t&1 (16 f32)
  const int rr = t >> 1;
  const int hh = t & 1;
  const int wr = (d0 + (rr >> 4)) * O_ + og + (rr & 15);   // W_d row
  const float* bptr = Wd + (size_t)wr * H2_ + hh * 16;
  const int bsw = (rr >> 1) & 3;

  // fragment-read swizzled 16B slot
  const int sl = (lq ^ ((lr >> 1) & 3)) * 8;

  f32x4 acc[4][4];
  #pragma unroll
  for (int mi = 0; mi < 4; ++mi)
    #pragma unroll
    for (int nj = 0; nj < 4; ++nj) acc[mi][nj] = f32x4{0.f, 0.f, 0.f, 0.f};

  f32x4 breg[4];

  auto stageA = [&](int k, int bf) {
    #pragma unroll
    for (int c = 0; c < 2; ++c)
      gload_lds16(aptr[c] + k * 32, &As[bf][(w * 32 + c * 16) * 32]);
  };
  auto loadB = [&](int k) {
    const float* p = bptr + k * 32;
    breg[0] = *(const f32x4*)p;
    breg[1] = *(const f32x4*)(p + 4);
    breg[2] = *(const f32x4*)(p + 8);
    breg[3] = *(const f32x4*)(p + 12);
  };
  auto writeB = [&](int bf) {
    S16u s0, s1;
    s0.u[0] = cvt_pk_bf16(breg[0].x, breg[0].y);
    s0.u[1] = cvt_pk_bf16(breg[0].z, breg[0].w);
    s0.u[2] = cvt_pk_bf16(breg[1].x, breg[1].y);
    s0.u[3] = cvt_pk_bf16(breg[1].z, breg[1].w);
    s1.u[0] = cvt_pk_bf16(breg[2].x, breg[2].y);
    s1.u[1] = cvt_pk_bf16(breg[2].z, breg[2].w);
    s1.u[2] = cvt_pk_bf16(breg[3].x, breg[3].y);
    s1.u[3] = cvt_pk_bf16(breg[3].z, breg[3].w);
    const int lcg0 = hh * 2;
    *(short8*)&Bs[bf][rr * 32 + (lcg0 ^ bsw) * 8]       = s0.v;
    *(short8*)&Bs[bf][rr * 32 + ((lcg0 + 1) ^ bsw) * 8] = s1.v;
  };

  // prologue: tile 0 into buf 0
  stageA(0, 0);
  loadB(0);
  asm volatile("s_waitcnt vmcnt(0)" ::: "memory");
  writeB(0);
  asm volatile("s_waitcnt lgkmcnt(0)" ::: "memory");
  __builtin_amdgcn_s_barrier();

  int buf = 0;
  for (int k = 0; k < 32; ++k) {
    if (k < 31) {
      stageA(k + 1, buf ^ 1);     // DMA next A tile into other buffer
      loadB(k + 1);               // issue next B loads (waited after MFMA)
    }

    // MFMA phase on buf: 8 ds_read_b128 + 16 MFMA
    short8 af[4], bfv[4];
    #pragma unroll
    for (int mi = 0; mi < 4; ++mi)
      af[mi] = *(const short8*)&As[buf][(wm + mi * 16 + lr) * 32 + sl];
    #pragma unroll
    for (int nj = 0; nj < 4; ++nj)
      bfv[nj] = *(const short8*)&Bs[buf][(wn + nj * 16 + lr) * 32 + sl];
    #pragma unroll
    for (int mi = 0; mi < 4; ++mi)
      #pragma unroll
      for (int nj = 0; nj < 4; ++nj)
        acc[mi][nj] = __builtin_amdgcn_mfma_f32_16x16x32_bf16(af[mi], bfv[nj],
                                                              acc[mi][nj], 0, 0, 0);

    if (k < 31) {
      asm volatile("s_waitcnt vmcnt(0)" ::: "memory");   // A DMA + B regs done
      writeB(buf ^ 1);
      asm volatile("s_waitcnt lgkmcnt(0)" ::: "memory");
      __builtin_amdgcn_s_barrier();
      buf ^= 1;
    }
  }

  // epilogue: fold this wave's 4 d (wn-half) + bias_d, one atomicAdd/(row,o)
  const int dbase = d0 + (w & 1) * 4;
  const int o     = og + lr;
  float bdv[4];
  #pragma unroll
  for (int nj = 0; nj < 4; ++nj)
    bdv[nj] = bd[(size_t)(dbase + nj) * O_ + o];
  #pragma unroll
  for (int mi = 0; mi < 4; ++mi)
    #pragma unroll
    for (int r = 0; r < 4; ++r) {
      const int row = bm + wm + mi * 16 + lq * 4 + r;
      f32x4 sc = *(const f32x4*)(inp + (size_t)row * D_ + dbase);
      float v = sc.x * (acc[mi][0][r] + bdv[0]) +
                sc.y * (acc[mi][1][r] + bdv[1]) +
                sc.z * (acc[mi][2][r] + bdv[2]) +
                sc.w * (acc[mi][3][r] + bdv[3]);
      atomicAdd(out + (size_t)row * O_ + o, v);
    }
}

extern "C" void kernel_launch(void* const* d_in, const int* in_sizes, int n_in,
                              void* d_out, int out_size, void* d_ws, size_t ws_size,
                              hipStream_t stream) {
  const float* input = (const float*)d_in[0];   // [512,256]
  const float* nanf  = (const float*)d_in[1];   // [512,256]
  const float* W_in  = (const float*)d_in[3];   // [512,256]
  const float* b_in  = (const float*)d_in[4];
  const float* W_h1  = (const float*)d_in[5];   // [1024,512]
  const float* b_h1  = (const float*)d_in[6];
  const float* W_h2  = (const float*)d_in[7];   // [1024,1024]
  const float* b_h2  = (const float*)d_in[8];
  const float* W_d   = (const float*)d_in[9];   // [65536,1024]
  const float* b_d   = (const float*)d_in[10];  // [65536]
  const float* W_b   = (const float*)d_in[11];  // [256,1024]
  const float* b_b   = (const float*)d_in[12];  // [256]
  float* out = (float*)d_out;                   // [512,256]

  float* x0 = (float*)d_ws;                     // [512,512]   1 MB
  float* x1 = x0 + 512 * 512;                   // [512,1024]  2 MB
  float* x2 = x1 + 512 * 1024;                  // [512,1024]  2 MB
  ushort_t* x2b = (ushort_t*)(x2 + 512 * 1024); // [512,1024] bf16, 1 MB

  // Stage A: MLP (~2 GFLOP, serial-dependent)
  gemm_bt64<1><<<dim3(512 / 64, 512 / 64), 256, 0, stream>>>(nanf, W_in, b_in, x0, 512, 512, 256);
  gemm_bt64<1><<<dim3(1024 / 64, 512 / 64), 256, 0, stream>>>(x0, W_h1, b_h1, x1, 512, 1024, 512);
  gemm_bt64<1><<<dim3(1024 / 64, 512 / 64), 256, 0, stream>>>(x1, W_h2, b_h2, x2, 512, 1024, 1024);
  cvt_f32_bf16<<<256, 256, 0, stream>>>(x2, x2b, 512 * 1024 / 8);
  // out = x2 @ W_b^T + b_b  (writes every element of poisoned d_out)
  gemm_bt64<0><<<dim3(256 / 64, 512 / 64), 256, 0, stream>>>(x2, W_b, b_b, out, 512, 256, 1024);
  // Stage B: bilinear contraction + folded bias_d (atomicAdd into out)
  stage_b5<<<dim3(8, 256), 256, 0, stream>>>(x2b, input, W_d, b_d, out);
}

// Round 5
// 568.442 us; speedup vs baseline: 1.0612x; 1.0276x over previous
//
#include <hip/hip_runtime.h>

#define B_  512
#define D_  256
#define O_  256
#define H2_ 1024

typedef __attribute__((ext_vector_type(4))) float  f32x4;
typedef __attribute__((ext_vector_type(8))) short  short8;
typedef __attribute__((ext_vector_type(4))) short  short4v;
typedef unsigned short ushort_t;

union S8u  { short4v v; unsigned u[2]; };
union S16u { short8  v; unsigned u[4]; };

// fp32 -> bf16 round-to-nearest-even on raw bits (finite inputs only)
__device__ __forceinline__ unsigned f32_bf16(float x) {
  unsigned u = __builtin_bit_cast(unsigned, x);
  return (u + 0x7fffu + ((u >> 16) & 1u)) >> 16;
}
__device__ __forceinline__ unsigned cvt_pk_bf16(float a, float b) {
  return f32_bf16(a) | (f32_bf16(b) << 16);
}

// async global->LDS, 16B per lane, wave-uniform LDS base + lane*16
__device__ __forceinline__ void gload_lds16(const void* g, void* l) {
  __builtin_amdgcn_global_load_lds(
      (const __attribute__((address_space(1))) unsigned*)g,
      (__attribute__((address_space(3))) unsigned*)l, 16, 0, 0);
}

// ---------------------------------------------------------------------------
// Generic small GEMM (unchanged — verified passing)
// ---------------------------------------------------------------------------
template <int RELU>
__global__ __launch_bounds__(256)
void gemm_bt64(const float* __restrict__ A, const float* __restrict__ Bm,
               const float* __restrict__ bias, float* __restrict__ C,
               int M, int N, int K) {
  __shared__ __align__(16) short As[64][72];
  __shared__ __align__(16) short Bs[64][72];
  const int t    = threadIdx.x;
  const int m0   = blockIdx.y * 64;
  const int n0   = blockIdx.x * 64;
  const int f4c  = t & 15;
  const int rg   = t >> 4;
  const int lane = t & 63;
  const int w    = t >> 6;
  const int wm   = (w & 1) * 32;
  const int wn   = (w >> 1) * 32;
  const int lr   = lane & 15;
  const int lq   = lane >> 4;

  f32x4 acc[2][2];
  #pragma unroll
  for (int i = 0; i < 2; ++i)
    #pragma unroll
    for (int j = 0; j < 2; ++j) acc[i][j] = f32x4{0.f, 0.f, 0.f, 0.f};

  for (int k0 = 0; k0 < K; k0 += 64) {
    #pragma unroll
    for (int j = 0; j < 4; ++j) {
      int r = rg + 16 * j;
      f32x4 av = *(const f32x4*)(A  + (size_t)(m0 + r) * K + k0 + f4c * 4);
      f32x4 bv = *(const f32x4*)(Bm + (size_t)(n0 + r) * K + k0 + f4c * 4);
      S8u sa; sa.u[0] = cvt_pk_bf16(av.x, av.y); sa.u[1] = cvt_pk_bf16(av.z, av.w);
      S8u sb; sb.u[0] = cvt_pk_bf16(bv.x, bv.y); sb.u[1] = cvt_pk_bf16(bv.z, bv.w);
      *(short4v*)&As[r][f4c * 4] = sa.v;
      *(short4v*)&Bs[r][f4c * 4] = sb.v;
    }
    __syncthreads();
    #pragma unroll
    for (int ks = 0; ks < 2; ++ks) {
      short8 a0 = *(const short8*)&As[wm + lr     ][ks * 32 + lq * 8];
      short8 a1 = *(const short8*)&As[wm + 16 + lr][ks * 32 + lq * 8];
      short8 b0 = *(const short8*)&Bs[wn + lr     ][ks * 32 + lq * 8];
      short8 b1 = *(const short8*)&Bs[wn + 16 + lr][ks * 32 + lq * 8];
      acc[0][0] = __builtin_amdgcn_mfma_f32_16x16x32_bf16(a0, b0, acc[0][0], 0, 0, 0);
      acc[0][1] = __builtin_amdgcn_mfma_f32_16x16x32_bf16(a0, b1, acc[0][1], 0, 0, 0);
      acc[1][0] = __builtin_amdgcn_mfma_f32_16x16x32_bf16(a1, b0, acc[1][0], 0, 0, 0);
      acc[1][1] = __builtin_amdgcn_mfma_f32_16x16x32_bf16(a1, b1, acc[1][1], 0, 0, 0);
    }
    __syncthreads();
  }
  #pragma unroll
  for (int mi = 0; mi < 2; ++mi)
    #pragma unroll
    for (int ni = 0; ni < 2; ++ni)
      #pragma unroll
      for (int r = 0; r < 4; ++r) {
        int row = m0 + wm + mi * 16 + lq * 4 + r;
        int col = n0 + wn + ni * 16 + lr;
        float v = acc[mi][ni][r] + bias[col];
        if (RELU) v = fmaxf(v, 0.f);
        C[(size_t)row * N + col] = v;
      }
}

// ---------------------------------------------------------------------------
// Bulk fp32 -> bf16 conversion (x2 only; 1 MB out, ~2 us)
// ---------------------------------------------------------------------------
__global__ __launch_bounds__(256)
void cvt_f32_bf16(const float* __restrict__ in, ushort_t* __restrict__ out, int n8) {
  for (size_t i = (size_t)blockIdx.x * 256 + threadIdx.x; i < (size_t)n8;
       i += (size_t)gridDim.x * 256) {
    const float* p = in + i * 8;
    f32x4 v0 = *(const f32x4*)p;
    f32x4 v1 = *(const f32x4*)(p + 4);
    S16u s;
    s.u[0] = cvt_pk_bf16(v0.x, v0.y);
    s.u[1] = cvt_pk_bf16(v0.z, v0.w);
    s.u[2] = cvt_pk_bf16(v1.x, v1.y);
    s.u[3] = cvt_pk_bf16(v1.z, v1.w);
    *(short8*)(out + i * 8) = s.v;
  }
}

// ---------------------------------------------------------------------------
// Stage B v6: same tiling as v5 (block 128x128: 128 rows x [8 d x 16 o]),
// two fixes vs v5:
//  1) NO ATOMICS: after an in-LDS wn-fold, each block writes ONE plain store
//     per (row,o) into part[dg][row][o-slab] (16 MB, L3-resident). A reduce
//     kernel sums the 32 dg-slabs into out. (v5's 8.4M device-scope RMWs =
//     32MB WRITE_SIZE, 64-way serialized per word, was a ~100us tail.)
//  2) COUNTED vmcnt pipeline (T4): writeB happens BEFORE the MFMA phase;
//     steady state waits are vmcnt(2) [B(k+1) regs] and vmcnt(4) [A(k+1)
//     DMA, B(k+2) stays in flight across the barrier]. Never drains to 0.
// launch_bounds(256,4): acc 64 AGPR + ~60 VGPR fits 128 -> 4 blocks/CU.
// XOR swizzle slot^=((row>>1)&3) on DMA source, ds_write, ds_read (verified
// zero conflicts in v4/v5). Dispatch: x=XCD, mt-siblings consecutive on one
// XCD -> W_d panel L2-dedup (FETCH 141MB verified in v5).
// ---------------------------------------------------------------------------
__global__ __launch_bounds__(256, 4)
void stage_b6(const ushort_t* __restrict__ x2b, const float* __restrict__ inp,
              const float* __restrict__ Wd, const float* __restrict__ bd,
              float* __restrict__ part) {
  __shared__ __align__(16) ushort_t As[2][128 * 32];   // 2 x 8KB
  __shared__ __align__(16) ushort_t Bs[2][128 * 32];   // 2 x 8KB
  const int t    = threadIdx.x;
  const int x    = blockIdx.x;              // XCD id under %8 round-robin
  const int q    = blockIdx.y;
  const int mt   = q & 3;
  const int nb   = (q >> 2) * 8 + x;        // 0..511
  const int dg   = nb >> 4;                 // 0..31
  const int d0   = dg * 8;
  const int og   = (nb & 15) * 16;
  const int bm   = mt * 128;
  const int lane = t & 63;
  const int w    = t >> 6;                  // 0..3
  const int wm   = (w >> 1) * 64;
  const int wn   = (w & 1) * 64;
  const int lr   = lane & 15;
  const int lq   = lane >> 4;

  // A staging (DMA): wave w, call c stages rows w*32+c*16+arow; source
  // col-group pre-swizzled (involution, rule 21).
  const int arow = lane >> 2;
  const int aswz = (lane & 3) ^ ((arow >> 1) & 3);
  const ushort_t* aptr[2];
  #pragma unroll
  for (int c = 0; c < 2; ++c)
    aptr[c] = x2b + (size_t)(bm + w * 32 + c * 16 + arow) * H2_ + aswz * 8;

  // B staging: thread covers LDS row rr=t>>1 (n-index), h-half hh=t&1
  const int rr = t >> 1;
  const int hh = t & 1;
  const int wr = (d0 + (rr >> 4)) * O_ + og + (rr & 15);   // W_d row
  const float* bptr = Wd + (size_t)wr * H2_ + hh * 16;
  const int bsw = (rr >> 1) & 3;

  // fragment-read swizzled 16B slot
  const int sl = (lq ^ ((lr >> 1) & 3)) * 8;

  f32x4 acc[4][4];
  #pragma unroll
  for (int mi = 0; mi < 4; ++mi)
    #pragma unroll
    for (int nj = 0; nj < 4; ++nj) acc[mi][nj] = f32x4{0.f, 0.f, 0.f, 0.f};

  f32x4 breg[4];

  auto stageA = [&](int k, int bf) {
    #pragma unroll
    for (int c = 0; c < 2; ++c)
      gload_lds16(aptr[c] + k * 32, &As[bf][(w * 32 + c * 16) * 32]);
  };
  auto loadB = [&](int k) {
    const float* p = bptr + k * 32;
    breg[0] = *(const f32x4*)p;
    breg[1] = *(const f32x4*)(p + 4);
    breg[2] = *(const f32x4*)(p + 8);
    breg[3] = *(const f32x4*)(p + 12);
  };
  auto writeB = [&](int bf) {
    S16u s0, s1;
    s0.u[0] = cvt_pk_bf16(breg[0].x, breg[0].y);
    s0.u[1] = cvt_pk_bf16(breg[0].z, breg[0].w);
    s0.u[2] = cvt_pk_bf16(breg[1].x, breg[1].y);
    s0.u[3] = cvt_pk_bf16(breg[1].z, breg[1].w);
    s1.u[0] = cvt_pk_bf16(breg[2].x, breg[2].y);
    s1.u[1] = cvt_pk_bf16(breg[2].z, breg[2].w);
    s1.u[2] = cvt_pk_bf16(breg[3].x, breg[3].y);
    s1.u[3] = cvt_pk_bf16(breg[3].z, breg[3].w);
    const int lcg0 = hh * 2;
    *(short8*)&Bs[bf][rr * 32 + (lcg0 ^ bsw) * 8]       = s0.v;
    *(short8*)&Bs[bf][rr * 32 + ((lcg0 + 1) ^ bsw) * 8] = s1.v;
  };

  // prologue: tile 0 into buf 0; B(1) left in flight
  stageA(0, 0);
  loadB(0);
  asm volatile("s_waitcnt vmcnt(0)" ::: "memory");
  __builtin_amdgcn_sched_barrier(0);
  writeB(0);
  loadB(1);
  asm volatile("s_waitcnt lgkmcnt(0)" ::: "memory");
  __builtin_amdgcn_s_barrier();

  int buf = 0;
  for (int k = 0; k < 32; ++k) {
    // entry: As[buf]=A(k), Bs[buf]=B(k); in flight: B(k+1)[4]
    if (k < 31) {
      stageA(k + 1, buf ^ 1);             // +2 DMA -> flight: B(k+1)4 A(k+1)2
      asm volatile("s_waitcnt vmcnt(2)" ::: "memory");  // B(k+1) regs ready
      __builtin_amdgcn_sched_barrier(0);
      writeB(buf ^ 1);                    // breg -> Bs[buf^1]
      if (k < 30) loadB(k + 2);           // +4 -> flight: A(k+1)2 B(k+2)4
    }

    // MFMA phase on buf: 8 ds_read_b128 + 16 MFMA (loads fly underneath)
    short8 af[4], bfv[4];
    #pragma unroll
    for (int mi = 0; mi < 4; ++mi)
      af[mi] = *(const short8*)&As[buf][(wm + mi * 16 + lr) * 32 + sl];
    #pragma unroll
    for (int nj = 0; nj < 4; ++nj)
      bfv[nj] = *(const short8*)&Bs[buf][(wn + nj * 16 + lr) * 32 + sl];
    #pragma unroll
    for (int mi = 0; mi < 4; ++mi)
      #pragma unroll
      for (int nj = 0; nj < 4; ++nj)
        acc[mi][nj] = __builtin_amdgcn_mfma_f32_16x16x32_bf16(af[mi], bfv[nj],
                                                              acc[mi][nj], 0, 0, 0);

    if (k < 31) {
      // A(k+1) DMA done; B(k+2) REMAINS in flight across the barrier (T4)
      if (k < 30) { asm volatile("s_waitcnt vmcnt(4)" ::: "memory"); }
      else        { asm volatile("s_waitcnt vmcnt(0)" ::: "memory"); }
      asm volatile("s_waitcnt lgkmcnt(0)" ::: "memory");
      __builtin_amdgcn_s_barrier();
      buf ^= 1;
    }
  }
  __builtin_amdgcn_sched_barrier(0);

  // epilogue: v[mi][r] = sum_nj inp*(acc+bd); fold the two wn-halves via LDS
  // (stride-17 scratch, no conflicts), ONE plain store per (row,o) to part.
  const int dbase = d0 + (w & 1) * 4;
  const int o     = og + lr;
  float bdv[4];
  #pragma unroll
  for (int nj = 0; nj < 4; ++nj)
    bdv[nj] = bd[(size_t)(dbase + nj) * O_ + o];

  float v[4][4];
  #pragma unroll
  for (int mi = 0; mi < 4; ++mi)
    #pragma unroll
    for (int r = 0; r < 4; ++r) {
      const int row = bm + wm + mi * 16 + lq * 4 + r;
      f32x4 sc = *(const f32x4*)(inp + (size_t)row * D_ + dbase);
      v[mi][r] = sc.x * (acc[mi][0][r] + bdv[0]) +
                 sc.y * (acc[mi][1][r] + bdv[1]) +
                 sc.z * (acc[mi][2][r] + bdv[2]) +
                 sc.w * (acc[mi][3][r] + bdv[3]);
    }

  __syncthreads();                         // all LDS reads done; reuse As
  float* lf = (float*)As;                  // 128 x 16, stride 17 (8.7KB)
  if (w & 1) {
    #pragma unroll
    for (int mi = 0; mi < 4; ++mi)
      #pragma unroll
      for (int r = 0; r < 4; ++r) {
        const int rl = wm + mi * 16 + lq * 4 + r;
        lf[rl * 17 + lr] = v[mi][r];
      }
  }
  __syncthreads();
  if (!(w & 1)) {
    float* pb = part + (size_t)dg * (B_ * O_);
    #pragma unroll
    for (int mi = 0; mi < 4; ++mi)
      #pragma unroll
      for (int r = 0; r < 4; ++r) {
        const int rl = wm + mi * 16 + lq * 4 + r;
        pb[(size_t)(bm + rl) * O_ + o] = v[mi][r] + lf[rl * 17 + lr];
      }
  }
}

// ---------------------------------------------------------------------------
// out[b,o] += sum_{dg<32} part[dg][b][o]   (16 MB read, L3-resident, ~8 us)
// ---------------------------------------------------------------------------
__global__ __launch_bounds__(256)
void reduce_parts(const float* __restrict__ part, float* __restrict__ out) {
  const int b = blockIdx.x;
  const int o = threadIdx.x;
  const size_t idx = (size_t)b * O_ + o;
  float s = 0.f;
  #pragma unroll 8
  for (int j = 0; j < 32; ++j)
    s += part[(size_t)j * (B_ * O_) + idx];
  out[idx] += s;
}

extern "C" void kernel_launch(void* const* d_in, const int* in_sizes, int n_in,
                              void* d_out, int out_size, void* d_ws, size_t ws_size,
                              hipStream_t stream) {
  const float* input = (const float*)d_in[0];   // [512,256]
  const float* nanf  = (const float*)d_in[1];   // [512,256]
  const float* W_in  = (const float*)d_in[3];   // [512,256]
  const float* b_in  = (const float*)d_in[4];
  const float* W_h1  = (const float*)d_in[5];   // [1024,512]
  const float* b_h1  = (const float*)d_in[6];
  const float* W_h2  = (const float*)d_in[7];   // [1024,1024]
  const float* b_h2  = (const float*)d_in[8];
  const float* W_d   = (const float*)d_in[9];   // [65536,1024]
  const float* b_d   = (const float*)d_in[10];  // [65536]
  const float* W_b   = (const float*)d_in[11];  // [256,1024]
  const float* b_b   = (const float*)d_in[12];  // [256]
  float* out = (float*)d_out;                   // [512,256]

  float* x0 = (float*)d_ws;                     // [512,512]   1 MB
  float* x1 = x0 + 512 * 512;                   // [512,1024]  2 MB
  float* x2 = x1 + 512 * 1024;                  // [512,1024]  2 MB
  ushort_t* x2b = (ushort_t*)(x2 + 512 * 1024); // [512,1024] bf16, 1 MB
  float* part = (float*)((char*)d_ws + 8ull * 1024 * 1024);  // 32x[512,256] 16MB

  // Stage A: MLP (~2 GFLOP, serial-dependent)
  gemm_bt64<1><<<dim3(512 / 64, 512 / 64), 256, 0, stream>>>(nanf, W_in, b_in, x0, 512, 512, 256);
  gemm_bt64<1><<<dim3(1024 / 64, 512 / 64), 256, 0, stream>>>(x0, W_h1, b_h1, x1, 512, 1024, 512);
  gemm_bt64<1><<<dim3(1024 / 64, 512 / 64), 256, 0, stream>>>(x1, W_h2, b_h2, x2, 512, 1024, 1024);
  cvt_f32_bf16<<<256, 256, 0, stream>>>(x2, x2b, 512 * 1024 / 8);
  // out = x2 @ W_b^T + b_b  (writes every element of poisoned d_out)
  gemm_bt64<0><<<dim3(256 / 64, 512 / 64), 256, 0, stream>>>(x2, W_b, b_b, out, 512, 256, 1024);
  // Stage B: bilinear contraction + folded bias_d -> partials (no atomics)
  stage_b6<<<dim3(8, 256), 256, 0, stream>>>(x2b, input, W_d, b_d, part);
  // out += sum of the 32 d-group partial slabs
  reduce_parts<<<512, 256, 0, stream>>>(part, out);
}